// Round 1
// baseline (155.298 us; speedup 1.0000x reference)
//
#include <hip/hip_runtime.h>

// Problem constants
#define HW_   10816          // 104*104
#define W_    104
#define T_    50             // targets per batch
#define NB_   32             // batch
#define NA_   3              // anchors
#define NCH_  75             // 3*(4+21)
#define F4PP_ 2704           // float4s per plane (10816/4)
#define NPLANES_ 96          // 32*3 conf planes
#define TOTAL_F4_ (NPLANES_ * F4PP_)
#define APART_ 512           // blocks for the big conf reduction

struct PosRec { int cell; float tx, ty, tw, th; unsigned m; };  // 24 B

__device__ __forceinline__ float sigf(float z) { return 1.0f / (1.0f + expf(-z)); }
__device__ __forceinline__ float clog(float p) { return fmaxf(logf(p), -100.0f); }
// f(z) = -clip(log(1 - sigmoid(z)), -100): contribution of a noobj=1 cell
__device__ __forceinline__ float fobj(float z) { float c = sigf(z); return -clog(1.0f - c); }
__device__ __forceinline__ float bce(float p, float t) {
    return -(t * clog(p) + (1.0f - t) * clog(1.0f - p));
}

// K1: per-batch target processing. Replicates JAX scatter semantics:
//  - positive cells: last-t-wins for tx/ty/tw/th, class bits are a union
//  - noobj zero cells: dedup'd set (first occurrence is the representative)
// Also zeroes the accumulators (block 0).
__global__ __launch_bounds__(256) void k_prep(const float* __restrict__ tgt,
                                              double* __restrict__ acc,
                                              int* __restrict__ npos,
                                              PosRec* __restrict__ pos,
                                              int* __restrict__ nocell)
{
    const float AW[3] = {14.5f, 19.5f, 46.625f};   // ANCHORS / 8
    const float AH[3] = {11.25f, 24.75f, 40.75f};
    int b = blockIdx.x;
    int u = threadIdx.x;
    __shared__ int s_pcell[T_], s_cls[T_], s_cond[T_], s_gi[T_], s_gj[T_];
    float r_tx = 0.f, r_ty = 0.f, r_tw = 0.f, r_th = 0.f;

    if (b == 0) { if (u < 8) acc[u] = 0.0; if (u == 8) *npos = 0; }

    if (u < T_) {
        const float* tp = tgt + ((size_t)b * T_ + u) * 5;
        float t0 = tp[0], t1 = tp[1], t2 = tp[2], t3 = tp[3], t4 = tp[4];
        bool valid = (t0 + t1 + t2 + t3 + t4) > 0.0f;
        float gx = t0 * 104.0f, gy = t1 * 104.0f, gw = t2 * 104.0f, gh = t3 * 104.0f;
        int gi = (int)gx, gj = (int)gy;
        float area_gt = (gw + 1.0f) * (gh + 1.0f);
        float iou[3];
        #pragma unroll
        for (int a = 0; a < 3; a++) {
            float inter = fmaxf(fminf(gw, AW[a]) + 1.0f, 0.0f) *
                          fmaxf(fminf(gh, AH[a]) + 1.0f, 0.0f);
            float area_a = (AW[a] + 1.0f) * (AH[a] + 1.0f);
            iou[a] = inter / (area_gt + area_a - inter + 1e-16f);
        }
        int best = 0;                       // argmax, first max wins
        if (iou[1] > iou[0]) best = 1;
        if (iou[2] > iou[best]) best = 2;
        bool inb = (unsigned)gi < 104u && (unsigned)gj < 104u;  // mode='drop'
        int cond = 0;
        #pragma unroll
        for (int a = 0; a < 3; a++) if (iou[a] > 0.5f) cond |= 1 << a;
        s_cond[u]  = (valid && inb) ? cond : 0;
        s_gi[u] = gi; s_gj[u] = gj;
        s_cls[u] = ((int)t4) & 31;
        s_pcell[u] = (valid && inb) ? (best * HW_ + gj * W_ + gi) : -1;
        r_tx = gx - (float)gi; r_ty = gy - (float)gj;
        r_tw = logf(gw / AW[best] + 1e-16f);
        r_th = logf(gh / AH[best] + 1e-16f);
    }
    __syncthreads();

    // Positive winners: thread t keeps its record iff no later target hits same cell.
    if (u < T_) {
        PosRec* slot = pos + b * T_ + u;
        int cell = s_pcell[u];
        if (cell >= 0) {
            bool win = true; unsigned m = 0;
            for (int tt = 0; tt < T_; tt++) {
                if (s_pcell[tt] == cell) {
                    if (tt > u) win = false;
                    m |= 1u << s_cls[tt];          // tcls is a union across all hits
                }
            }
            if (win) { slot->cell = cell; slot->tx = r_tx; slot->ty = r_ty;
                       slot->tw = r_tw; slot->th = r_th; slot->m = m; }
            else slot->cell = -1;
        } else slot->cell = -1;
    }

    // Noobj zero-set winners: item (t,a) active if valid & iou[a]>0.5; dedup per (a,gi,gj).
    int a = u >> 6, t = u & 63;
    if (a < 3 && t < T_) {
        int* nslot = nocell + b * (3 * T_) + a * T_ + t;
        int v = -1;
        if ((s_cond[t] >> a) & 1) {
            int gi = s_gi[t], gj = s_gj[t];
            bool win = true;
            for (int tt = 0; tt < t; tt++)
                if (((s_cond[tt] >> a) & 1) && s_gi[tt] == gi && s_gj[tt] == gj) { win = false; break; }
            if (win) v = a * HW_ + gj * W_ + gi;
        }
        *nslot = v;
    }
}

// K2: blocks [0, APART_): sum f(conf) over ALL cells (float4-vectorized, 3 conf planes
//     per batch). blocks [APART_, APART_+32): per-batch positive-cell losses and
//     noobj zero-set subtraction.
__global__ __launch_bounds__(256) void k_main(const float* __restrict__ in,
                                              double* __restrict__ acc,
                                              int* __restrict__ npos,
                                              const PosRec* __restrict__ pos,
                                              const int* __restrict__ nocell)
{
    if (blockIdx.x < APART_) {
        float local = 0.0f;
        for (int i = blockIdx.x * 256 + threadIdx.x; i < TOTAL_F4_; i += APART_ * 256) {
            int p = i / F4PP_;
            int q = i - p * F4PP_;
            int b = p / 3, a = p - b * 3;
            const float4* base = (const float4*)in + (size_t)(b * NCH_ + a * 25 + 4) * F4PP_;
            float4 v = base[q];
            local += fobj(v.x); local += fobj(v.y); local += fobj(v.z); local += fobj(v.w);
        }
        #pragma unroll
        for (int o = 32; o; o >>= 1) local += __shfl_down(local, o, 64);
        __shared__ float sred[4];
        if ((threadIdx.x & 63) == 0) sred[threadIdx.x >> 6] = local;
        __syncthreads();
        if (threadIdx.x == 0)
            atomicAdd(&acc[6], (double)(sred[0] + sred[1] + sred[2] + sred[3]));
    } else {
        int b = blockIdx.x - APART_;
        int u = threadIdx.x;
        const float* pb = in + (size_t)b * NCH_ * HW_;
        if (u < T_) {
            PosRec r = pos[b * T_ + u];
            if (r.cell >= 0) {
                int a = r.cell / HW_, pix = r.cell - a * HW_;
                const float* cp = pb + (size_t)a * 25 * HW_ + pix;
                float zx = cp[0], zy = cp[HW_], zw = cp[2 * HW_], zh = cp[3 * HW_], zc = cp[4 * HW_];
                atomicAdd(&acc[0], (double)bce(sigf(zx), r.tx));
                atomicAdd(&acc[1], (double)bce(sigf(zy), r.ty));
                float dw = zw - r.tw, dh = zh - r.th;
                atomicAdd(&acc[2], (double)(dw * dw));
                atomicAdd(&acc[3], (double)(dh * dh));
                atomicAdd(&acc[4], (double)(-clog(sigf(zc))));
                float cl = 0.0f;
                #pragma unroll
                for (int k = 0; k < 20; k++) {
                    float pcl = sigf(cp[(size_t)(5 + k) * HW_]);
                    cl += ((r.m >> k) & 1u) ? (-clog(pcl)) : (-clog(1.0f - pcl));
                }
                atomicAdd(&acc[5], (double)cl);
                atomicAdd(npos, 1);
            }
        } else if (u >= 64 && u < 64 + 3 * T_) {
            int c = nocell[b * (3 * T_) + (u - 64)];
            if (c >= 0) {
                int a = c / HW_, pix = c - a * HW_;
                float z = pb[(size_t)(a * 25 + 4) * HW_ + pix];
                atomicAdd(&acc[7], (double)fobj(z));
            }
        }
    }
}

// K3: combine into the 6 outputs.
__global__ void k_final(const double* __restrict__ acc, const int* __restrict__ npos,
                        float* __restrict__ out)
{
    if (threadIdx.x == 0 && blockIdx.x == 0) {
        const double N = 1038336.0;   // 32*3*104*104
        out[0] = (float)(acc[0] / N * 2.5);
        out[1] = (float)(acc[1] / N * 2.5);
        out[2] = (float)(acc[2] / N * 2.5);
        out[3] = (float)(acc[3] / N * 2.5);
        out[4] = (float)(acc[4] / N + 0.5 * ((acc[6] - acc[7]) / N));
        double denom = fmax((double)(*npos) * 20.0, 1.0);
        out[5] = (float)(acc[5] / denom);
    }
}

extern "C" void kernel_launch(void* const* d_in, const int* in_sizes, int n_in,
                              void* d_out, int out_size, void* d_ws, size_t ws_size,
                              hipStream_t stream)
{
    const float* in  = (const float*)d_in[0];   // (32, 75, 104, 104) fp32
    const float* tgt = (const float*)d_in[1];   // (32, 50, 5) fp32
    float* out = (float*)d_out;                 // 6 fp32
    char* ws = (char*)d_ws;
    double* acc  = (double*)ws;                 // 8 doubles (64 B)
    int* npos    = (int*)(ws + 64);             // 1 int
    PosRec* pos  = (PosRec*)(ws + 128);         // 32*50*24 = 38400 B
    int* nocell  = (int*)(ws + 128 + 38400);    // 32*150*4 = 19200 B

    k_prep <<<NB_, 256, 0, stream>>>(tgt, acc, npos, pos, nocell);
    k_main <<<APART_ + NB_, 256, 0, stream>>>(in, acc, npos, pos, nocell);
    k_final<<<1, 64, 0, stream>>>(acc, npos, out);
}

// Round 2
// 141.435 us; speedup vs baseline: 1.0980x; 1.0980x over previous
//
#include <hip/hip_runtime.h>

// Problem constants
#define HW_   10816          // 104*104
#define W_    104
#define T_    50             // targets per batch
#define NB_   32             // batch
#define NCH_  75             // 3*(4+21)
#define F4PP_ 2704           // float4s per plane (10816/4)
#define NPLANES_ 96          // 32*3 conf planes
#define TOTAL_F4_ (NPLANES_ * F4PP_)
#define APART_ 512           // blocks for the big conf reduction

__device__ __forceinline__ float sigf(float z) { return 1.0f / (1.0f + expf(-z)); }
__device__ __forceinline__ float clog(float p) { return fmaxf(logf(p), -100.0f); }
// f(z) = -clip(log(1 - sigmoid(z)), -100): contribution of a noobj=1 cell
__device__ __forceinline__ float fobj(float z) { float c = sigf(z); return -clog(1.0f - c); }
__device__ __forceinline__ float bce(float p, float t) {
    return -(t * clog(p) + (1.0f - t) * clog(1.0f - p));
}

// Kernel A:
//   blocks [0, APART_):       sum f(conf) over ALL cells -> pA[blk]  (no atomics)
//   blocks [APART_, APART_+32): batch b = blk-APART_: in-block target prep
//       (JAX scatter semantics: last-t-wins positives, class-bit union, dedup'd
//       noobj zero-set), positive losses + noobj subtraction, block reduce ->
//       pB[b*8 + {0:x,1:y,2:w,3:h,4:obj,5:cls,6:noobjsub,7:npos}]
__global__ __launch_bounds__(256) void k_main(const float* __restrict__ in,
                                              const float* __restrict__ tgt,
                                              double* __restrict__ pA,
                                              double* __restrict__ pB)
{
    if (blockIdx.x < APART_) {
        float local = 0.0f;
        for (int i = blockIdx.x * 256 + threadIdx.x; i < TOTAL_F4_; i += APART_ * 256) {
            int p = i / F4PP_;
            int q = i - p * F4PP_;
            int b = p / 3, a = p - b * 3;
            const float4* base = (const float4*)in + (size_t)(b * NCH_ + a * 25 + 4) * F4PP_;
            float4 v = base[q];
            local += fobj(v.x); local += fobj(v.y); local += fobj(v.z); local += fobj(v.w);
        }
        #pragma unroll
        for (int o = 32; o; o >>= 1) local += __shfl_down(local, o, 64);
        __shared__ float sred[4];
        if ((threadIdx.x & 63) == 0) sred[threadIdx.x >> 6] = local;
        __syncthreads();
        if (threadIdx.x == 0)
            pA[blockIdx.x] = (double)(sred[0] + sred[1] + sred[2] + sred[3]);
        return;
    }

    // ---- per-batch block ----
    const float AW[3] = {14.5f, 19.5f, 46.625f};   // ANCHORS / 8
    const float AH[3] = {11.25f, 24.75f, 40.75f};
    int b = blockIdx.x - APART_;
    int u = threadIdx.x;
    __shared__ int s_pcell[T_], s_cls[T_], s_cond[T_], s_gi[T_], s_gj[T_];
    float r_tx = 0.f, r_ty = 0.f, r_tw = 0.f, r_th = 0.f;

    if (u < T_) {
        const float* tp = tgt + ((size_t)b * T_ + u) * 5;
        float t0 = tp[0], t1 = tp[1], t2 = tp[2], t3 = tp[3], t4 = tp[4];
        bool valid = (t0 + t1 + t2 + t3 + t4) > 0.0f;
        float gx = t0 * 104.0f, gy = t1 * 104.0f, gw = t2 * 104.0f, gh = t3 * 104.0f;
        int gi = (int)gx, gj = (int)gy;
        float area_gt = (gw + 1.0f) * (gh + 1.0f);
        float iou[3];
        #pragma unroll
        for (int a = 0; a < 3; a++) {
            float inter = fmaxf(fminf(gw, AW[a]) + 1.0f, 0.0f) *
                          fmaxf(fminf(gh, AH[a]) + 1.0f, 0.0f);
            float area_a = (AW[a] + 1.0f) * (AH[a] + 1.0f);
            iou[a] = inter / (area_gt + area_a - inter + 1e-16f);
        }
        int best = 0;                       // argmax, first max wins
        if (iou[1] > iou[0]) best = 1;
        if (iou[2] > iou[best]) best = 2;
        bool inb = (unsigned)gi < 104u && (unsigned)gj < 104u;  // mode='drop'
        int cond = 0;
        #pragma unroll
        for (int a = 0; a < 3; a++) if (iou[a] > 0.5f) cond |= 1 << a;
        s_cond[u]  = (valid && inb) ? cond : 0;
        s_gi[u] = gi; s_gj[u] = gj;
        s_cls[u] = ((int)t4) & 31;
        s_pcell[u] = (valid && inb) ? (best * HW_ + gj * W_ + gi) : -1;
        r_tx = gx - (float)gi; r_ty = gy - (float)gj;
        r_tw = logf(gw / AW[best] + 1e-16f);
        r_th = logf(gh / AH[best] + 1e-16f);
    }
    __syncthreads();

    float ax = 0.f, ay = 0.f, aw2 = 0.f, ah2 = 0.f, aobj = 0.f, acls = 0.f,
          anoobj = 0.f, acnt = 0.f;
    const float* pb = in + (size_t)b * NCH_ * HW_;

    // Positive winners: thread t keeps its record iff no later target hits same cell.
    if (u < T_) {
        int cell = s_pcell[u];
        if (cell >= 0) {
            bool win = true; unsigned m = 0;
            for (int tt = 0; tt < T_; tt++) {
                if (s_pcell[tt] == cell) {
                    if (tt > u) win = false;
                    m |= 1u << s_cls[tt];          // tcls is a union across all hits
                }
            }
            if (win) {
                int a = cell / HW_, pix = cell - a * HW_;
                const float* cp = pb + (size_t)a * 25 * HW_ + pix;
                float zx = cp[0], zy = cp[HW_], zw = cp[2 * HW_], zh = cp[3 * HW_], zc = cp[4 * HW_];
                ax = bce(sigf(zx), r_tx);
                ay = bce(sigf(zy), r_ty);
                float dw = zw - r_tw, dh = zh - r_th;
                aw2 = dw * dw; ah2 = dh * dh;
                aobj = -clog(sigf(zc));
                #pragma unroll
                for (int k = 0; k < 20; k++) {
                    float pcl = sigf(cp[(size_t)(5 + k) * HW_]);
                    acls += ((m >> k) & 1u) ? (-clog(pcl)) : (-clog(1.0f - pcl));
                }
                acnt = 1.0f;
            }
        }
    } else if (u >= 64 && u < 64 + 3 * T_) {
        // Noobj zero-set winners: item (t,a) active if valid & iou[a]>0.5;
        // dedup per (a,gi,gj): first occurrence is the representative.
        int a = (u - 64) / T_, t = (u - 64) - a * T_;
        if ((s_cond[t] >> a) & 1) {
            int gi = s_gi[t], gj = s_gj[t];
            bool win = true;
            for (int tt = 0; tt < t; tt++)
                if (((s_cond[tt] >> a) & 1) && s_gi[tt] == gi && s_gj[tt] == gj) { win = false; break; }
            if (win) {
                float z = pb[(size_t)(a * 25 + 4) * HW_ + gj * W_ + gi];
                anoobj = fobj(z);
            }
        }
    }

    // Block reduction of 8 floats (4 waves -> LDS -> thread 0)
    float vals[8] = {ax, ay, aw2, ah2, aobj, acls, anoobj, acnt};
    #pragma unroll
    for (int k = 0; k < 8; k++)
        #pragma unroll
        for (int o = 32; o; o >>= 1) vals[k] += __shfl_down(vals[k], o, 64);
    __shared__ float sred2[4][8];
    if ((u & 63) == 0)
        #pragma unroll
        for (int k = 0; k < 8; k++) sred2[u >> 6][k] = vals[k];
    __syncthreads();
    if (u == 0) {
        #pragma unroll
        for (int k = 0; k < 8; k++)
            pB[b * 8 + k] = (double)(sred2[0][k] + sred2[1][k] + sred2[2][k] + sred2[3][k]);
    }
}

// Kernel B: reduce partials, emit the 6 outputs.
__global__ __launch_bounds__(256) void k_final(const double* __restrict__ pA,
                                               const double* __restrict__ pB,
                                               float* __restrict__ out)
{
    int u = threadIdx.x;
    __shared__ double s_conf;
    // sum pA[0..511]
    double s = pA[u] + pA[u + 256];
    #pragma unroll
    for (int o = 32; o; o >>= 1) s += __shfl_down(s, o, 64);
    __shared__ double sred[4];
    if ((u & 63) == 0) sred[u >> 6] = s;
    __syncthreads();
    if (u == 0) s_conf = sred[0] + sred[1] + sred[2] + sred[3];
    __syncthreads();

    if (u < 64) {   // wave 0: reduce the 32x8 batch partials
        double r[8];
        #pragma unroll
        for (int k = 0; k < 8; k++) r[k] = (u < NB_) ? pB[u * 8 + k] : 0.0;
        #pragma unroll
        for (int k = 0; k < 8; k++)
            #pragma unroll
            for (int o = 32; o; o >>= 1) r[k] += __shfl_down(r[k], o, 64);
        if (u == 0) {
            const double N = 1038336.0;   // 32*3*104*104
            out[0] = (float)(r[0] / N * 2.5);
            out[1] = (float)(r[1] / N * 2.5);
            out[2] = (float)(r[2] / N * 2.5);
            out[3] = (float)(r[3] / N * 2.5);
            out[4] = (float)(r[4] / N + 0.5 * ((s_conf - r[6]) / N));
            double denom = fmax(r[7] * 20.0, 1.0);
            out[5] = (float)(r[5] / denom);
        }
    }
}

extern "C" void kernel_launch(void* const* d_in, const int* in_sizes, int n_in,
                              void* d_out, int out_size, void* d_ws, size_t ws_size,
                              hipStream_t stream)
{
    const float* in  = (const float*)d_in[0];   // (32, 75, 104, 104) fp32
    const float* tgt = (const float*)d_in[1];   // (32, 50, 5) fp32
    float* out = (float*)d_out;                 // 6 fp32
    char* ws = (char*)d_ws;
    double* pA = (double*)ws;                   // 512 doubles (4096 B)
    double* pB = (double*)(ws + 4096);          // 32*8 doubles (2048 B)

    k_main <<<APART_ + NB_, 256, 0, stream>>>(in, tgt, pA, pB);
    k_final<<<1, 256, 0, stream>>>(pA, pB, out);
}